// Round 1
// baseline (393.292 us; speedup 1.0000x reference)
//
#include <hip/hip_runtime.h>

// Dtype-agnostic (device probe, folded into mlp_kernel): flags[0]=1 if floats are
// f32 (npz sizes say f32), flags[1]=1 if edge_index is int64.
// mlp_kernel: weights staged to LDS (transposed, padded) once per block; all MFMA
// fragments come from conflict-free ds_read_b128. Node tables written as bf16
// interleaved [node][batch][r] (one cache line per gathered node).
// edge_kernel: 2 edges/thread, vectorized idx loads + stores, gamma register-tiled
// per l; streaming traffic (eidx, out, X) marked non-temporal to keep the 6.4 MB
// gather tables L2-resident.
// d_ws layout: Atb u16[50000*32] | Btb u16[50000*32] | flags int[2]

typedef unsigned short u16;
typedef unsigned int   u32;
typedef __attribute__((ext_vector_type(8))) short short8;
typedef __attribute__((ext_vector_type(4))) float f32x4;
typedef __attribute__((ext_vector_type(2))) float f32x2;
typedef __attribute__((ext_vector_type(2))) long long ll2;
typedef __attribute__((ext_vector_type(2))) int i32x2;

#define N_NODES 50000
#define T_STEPS 8
#define C_DIM   64
#define HID     128
#define R_DIM   16
#define L_DIM   12
#define E_EDGES 1600000
#define TILES   6250        // (2*N_NODES)/16, exact; 3125 tiles per batch (no straddle)
#define HSTRIDE 136         // hid row stride (bf16 elems), 272B: b128-aligned, conflict-free
#define W1S     72          // w1t row stride (64+8)
#define W2S     136         // w2t row stride (128+8)
#define TAB_U16 ((size_t)N_NODES * 32)

__device__ __forceinline__ float bf2f(u16 u) {
  unsigned v = ((unsigned)u) << 16;
  return __builtin_bit_cast(float, v);
}
__device__ __forceinline__ u16 f2bf(float f) {
  unsigned x = __builtin_bit_cast(unsigned, f);
  x += 0x7fffu + ((x >> 16) & 1u);
  return (u16)(x >> 16);
}
__device__ __forceinline__ u16 ld_bf(const void* p, int idx, bool f32) {
  return f32 ? f2bf(((const float*)p)[idx]) : ((const u16*)p)[idx];
}
__device__ __forceinline__ float ld_f(const void* p, int idx, bool f32) {
  return f32 ? ((const float*)p)[idx] : bf2f(((const u16*)p)[idx]);
}

// ---------------------------------------------------------------------------
// Kernel 1: node MLPs. One wave = 16 nodes. All weights in LDS.
// Dtype detection inlined (identical test to the old detect_kernel); block 0
// publishes flags for edge_kernel.
// LDS: w1t[2][128][72] + w2t[2][16][136] + hid[4][16][136] + biases = 64.1 KB
// ---------------------------------------------------------------------------
__global__ __launch_bounds__(256, 2) void mlp_kernel(
    const void* __restrict__ X, const void* __restrict__ eidx,
    const void* __restrict__ W1s, const void* __restrict__ b1s,
    const void* __restrict__ W2s, const void* __restrict__ b2s,
    const void* __restrict__ W1d, const void* __restrict__ b1d,
    const void* __restrict__ W2d, const void* __restrict__ b2d,
    u16* __restrict__ Atb, u16* __restrict__ Btb,
    int* __restrict__ flags)
{
  __shared__ u16 w1t[2 * HID * W1S];       // [m][n][k] (transposed W1), 36864 B
  __shared__ u16 w2t[2 * R_DIM * W2S];     // [m][r][k] (transposed W2),  8704 B
  __shared__ u16 hidb[4 * 16 * HSTRIDE];   // [wave][row][col],          17408 B
  __shared__ float b1l[2 * HID];           //                             1024 B
  __shared__ float b2l[2 * R_DIM];         //                              128 B
  __shared__ int s_cnt, s_zcnt;

  const int tid  = threadIdx.x;
  const int wave = tid >> 6;
  const int lane = tid & 63;
  const int nl   = lane & 15;
  const int quad = lane >> 4;

  // ---- inline dtype detection (same statistics as the old detect_kernel) ----
  if (tid == 0) { s_cnt = 0; s_zcnt = 0; }
  __syncthreads();
  {
    int c = 0;
    const u16* w1u = (const u16*)W1s;
#pragma unroll
    for (int i = 0; i < 8; ++i) {
      u16 u = w1u[tid * 8 + i];
      int ex = (u >> 7) & 0xFF;
      if (ex >= 100 && ex <= 127) c++;
    }
    atomicAdd(&s_cnt, c);
    if (tid < 64 && ((const u32*)eidx)[2 * tid + 1] == 0) atomicAdd(&s_zcnt, 1);
  }
  __syncthreads();
  const bool isf32 = s_cnt < 1638;
  if (blockIdx.x == 0 && tid == 0) {
    flags[0] = isf32 ? 1 : 0;
    flags[1] = (s_zcnt == 64) ? 1 : 0;
  }

  const void* W1p[2] = {W1s, W1d};
  const void* W2p[2] = {W2s, W2d};
  const void* b1p[2] = {b1s, b1d};
  const void* b2p[2] = {b2s, b2d};

  // ---- cooperative staging: global (coalesced reads) -> LDS (transposed) ----
#pragma unroll
  for (int m = 0; m < 2; ++m) {
    for (int f = tid; f < C_DIM * HID; f += 256) {       // W1 (64,128) -> w1t[m][n][k]
      int k = f >> 7, n = f & 127;
      w1t[m * HID * W1S + n * W1S + k] = ld_bf(W1p[m], f, isf32);
    }
    for (int f = tid; f < HID * R_DIM; f += 256) {       // W2 (128,16) -> w2t[m][r][k]
      int k = f >> 4, r = f & 15;
      w2t[m * R_DIM * W2S + r * W2S + k] = ld_bf(W2p[m], f, isf32);
    }
    if (tid < HID)   b1l[m * HID + tid]   = ld_f(b1p[m], tid, isf32);
    if (tid < R_DIM) b2l[m * R_DIM + tid] = ld_f(b2p[m], tid, isf32);
  }
  __syncthreads();

  float b1v[2][8], b2v[2];
#pragma unroll
  for (int m = 0; m < 2; ++m) {
#pragma unroll
    for (int ct = 0; ct < 8; ++ct) b1v[m][ct] = b1l[m * HID + ct * 16 + nl];
    b2v[m] = b2l[m * R_DIM + nl];
  }

  u16* hw = hidb + wave * 16 * HSTRIDE;

  for (int tile = blockIdx.x * 4 + wave; tile < TILES; tile += gridDim.x * 4) {
    const int g0 = tile * 16;
    const int g = g0 + nl;
    const int bb = (g >= N_NODES) ? 1 : 0;
    const int n = g - bb * N_NODES;
    const size_t rowoff = ((size_t)(bb * T_STEPS + T_STEPS - 1) * N_NODES + n) * C_DIM;

    // A-frag for layer1: A[m=nl][k=quad*8+j (+32)]. X is streamed once: nt loads.
    short8 af0, af1;
    if (isf32) {
      const float* xf = (const float*)X + rowoff;
      f32x4 x0 = __builtin_nontemporal_load((const f32x4*)(xf + quad * 8));
      f32x4 x1 = __builtin_nontemporal_load((const f32x4*)(xf + quad * 8 + 4));
      f32x4 x2 = __builtin_nontemporal_load((const f32x4*)(xf + 32 + quad * 8));
      f32x4 x3 = __builtin_nontemporal_load((const f32x4*)(xf + 32 + quad * 8 + 4));
#pragma unroll
      for (int j = 0; j < 4; ++j) {
        af0[j]     = (short)f2bf(x0[j]);
        af0[4 + j] = (short)f2bf(x1[j]);
        af1[j]     = (short)f2bf(x2[j]);
        af1[4 + j] = (short)f2bf(x3[j]);
      }
    } else {
      const u16* xb = (const u16*)X + rowoff;
      af0 = __builtin_nontemporal_load((const short8*)(xb + quad * 8));
      af1 = __builtin_nontemporal_load((const short8*)(xb + 32 + quad * 8));
    }

#pragma unroll
    for (int m = 0; m < 2; ++m) {
      const u16* w1m = w1t + m * HID * W1S;
      // layer1: hidden[16 nodes][128 units], relu, -> hid LDS (bf16)
#pragma unroll
      for (int ct = 0; ct < 8; ++ct) {
        f32x4 acc = {b1v[m][ct], b1v[m][ct], b1v[m][ct], b1v[m][ct]};
        short8 bf0 = *(const short8*)(w1m + (ct * 16 + nl) * W1S + quad * 8);
        short8 bf1 = *(const short8*)(w1m + (ct * 16 + nl) * W1S + 32 + quad * 8);
        acc = __builtin_amdgcn_mfma_f32_16x16x32_bf16(af0, bf0, acc, 0, 0, 0);
        acc = __builtin_amdgcn_mfma_f32_16x16x32_bf16(af1, bf1, acc, 0, 0, 0);
#pragma unroll
        for (int i = 0; i < 4; ++i) {
          float h = acc[i] > 0.f ? acc[i] : 0.f;
          hw[(quad * 4 + i) * HSTRIDE + ct * 16 + nl] = f2bf(h);
        }
      }
      // layer2: A2[m=nl][k] from hid; B2[k][r=nl] from w2t
      const u16* w2m = w2t + m * R_DIM * W2S;
      f32x4 acc2 = {b2v[m], b2v[m], b2v[m], b2v[m]};
#pragma unroll
      for (int kt = 0; kt < 4; ++kt) {
        short8 a2  = *(const short8*)(hw + nl * HSTRIDE + kt * 32 + quad * 8);
        short8 b2f = *(const short8*)(w2m + nl * W2S + kt * 32 + quad * 8);
        acc2 = __builtin_amdgcn_mfma_f32_16x16x32_bf16(a2, b2f, acc2, 0, 0, 0);
      }
      u16* outp = (m == 0) ? Atb : Btb;
      // D[row=quad*4+i][col=nl=r] -> tab[node][batch][r] (bf16, 64B/node row)
#pragma unroll
      for (int i = 0; i < 4; ++i) {
        int gg = g0 + quad * 4 + i;
        int bo = (gg >= N_NODES) ? 1 : 0;
        int nn = gg - bo * N_NODES;
        outp[(size_t)nn * 32 + bo * 16 + nl] = f2bf(acc2[i]);
      }
    }
  }
}

// ---------------------------------------------------------------------------
// Kernel 2: edge scoring. Two edges per thread; one 64B gather line per node.
// grid = E/512 = 3125 blocks exactly. Streaming loads/stores are non-temporal
// so Atb/Btb (6.4 MB) stay L2-resident for the random gathers.
// ---------------------------------------------------------------------------
__global__ __launch_bounds__(256, 4) void edge_kernel(
    const void* __restrict__ eidx,
    const u16* __restrict__ Atb, const u16* __restrict__ Btb,
    const void* __restrict__ gamma, void* __restrict__ out,
    const int* __restrict__ flags)
{
  __shared__ float gf[L_DIM * R_DIM];
  const bool isf32 = flags[0] != 0;
  const bool isi64 = flags[1] != 0;
  const int tid = threadIdx.x;
  if (tid < L_DIM * R_DIM) gf[tid] = ld_f(gamma, tid, isf32);
  __syncthreads();

  const int e0 = (blockIdx.x * 256 + tid) * 2;
  int inode0, inode1, jnode0, jnode1;
  if (isi64) {
    ll2 vi = __builtin_nontemporal_load((const ll2*)((const long long*)eidx + e0));
    ll2 vj = __builtin_nontemporal_load((const ll2*)((const long long*)eidx + E_EDGES + e0));
    inode0 = (int)vi[0]; inode1 = (int)vi[1];
    jnode0 = (int)vj[0]; jnode1 = (int)vj[1];
  } else {
    i32x2 vi = __builtin_nontemporal_load((const i32x2*)((const int*)eidx + e0));
    i32x2 vj = __builtin_nontemporal_load((const i32x2*)((const int*)eidx + E_EDGES + e0));
    inode0 = vi[0]; inode1 = vi[1];
    jnode0 = vj[0]; jnode1 = vj[1];
  }

  // p0 = batch0 products, p1 = batch1 products; slot s = edge e0+s.
  float p0[2][16], p1[2][16];
#pragma unroll
  for (int s = 0; s < 2; ++s) {
    const int in = s ? inode1 : inode0;
    const int jn = s ? jnode1 : jnode0;
    const short8* ar = (const short8*)(Atb + (size_t)in * 32);
    const short8* br = (const short8*)(Btb + (size_t)jn * 32);
    short8 a0 = ar[0], a1 = ar[1], a2 = ar[2], a3 = ar[3];
    short8 b0 = br[0], b1 = br[1], b2 = br[2], b3 = br[3];
#pragma unroll
    for (int j = 0; j < 8; ++j) {
      p0[s][j]     = bf2f((u16)a0[j]) * bf2f((u16)b0[j]);
      p0[s][8 + j] = bf2f((u16)a1[j]) * bf2f((u16)b1[j]);
      p1[s][j]     = bf2f((u16)a2[j]) * bf2f((u16)b2[j]);
      p1[s][8 + j] = bf2f((u16)a3[j]) * bf2f((u16)b3[j]);
    }
  }

  float* outf = (float*)out;
  u16*   outh = (u16*)out;
#pragma unroll 2
  for (int l = 0; l < L_DIM; ++l) {
    const f32x4* gr = (const f32x4*)(gf + l * R_DIM);
    f32x4 g0 = gr[0], g1 = gr[1], g2 = gr[2], g3 = gr[3];
    float s00 = 0.f, s01 = 0.f, s10 = 0.f, s11 = 0.f;
#pragma unroll
    for (int r = 0; r < 16; ++r) {   // accumulation order matches prior kernel
      float g = (r < 4) ? g0[r] : (r < 8) ? g1[r - 4] : (r < 12) ? g2[r - 8] : g3[r - 12];
      s00 = fmaf(g, p0[0][r], s00);
      s01 = fmaf(g, p0[1][r], s01);
      s10 = fmaf(g, p1[0][r], s10);
      s11 = fmaf(g, p1[1][r], s11);
    }
    size_t o0 = (size_t)l * E_EDGES + e0;
    size_t o1 = (size_t)(L_DIM + l) * E_EDGES + e0;
    if (isf32) {
      f32x2 v0 = {s00, s01};
      f32x2 v1 = {s10, s11};
      __builtin_nontemporal_store(v0, (f32x2*)(outf + o0));
      __builtin_nontemporal_store(v1, (f32x2*)(outf + o1));
    } else {
      u32 w0 = (u32)f2bf(s00) | ((u32)f2bf(s01) << 16);
      u32 w1 = (u32)f2bf(s10) | ((u32)f2bf(s11) << 16);
      __builtin_nontemporal_store(w0, (u32*)(outh + o0));
      __builtin_nontemporal_store(w1, (u32*)(outh + o1));
    }
  }
}

extern "C" void kernel_launch(void* const* d_in, const int* in_sizes, int n_in,
                              void* d_out, int out_size, void* d_ws, size_t ws_size,
                              hipStream_t stream) {
  const void* X     = d_in[0];
  const void* eidx  = d_in[1];
  const void* W1s   = d_in[2];
  const void* b1s   = d_in[3];
  const void* W2s   = d_in[4];
  const void* b2s   = d_in[5];
  const void* W1d   = d_in[6];
  const void* b1d   = d_in[7];
  const void* W2d   = d_in[8];
  const void* b2d   = d_in[9];
  const void* gamma = d_in[10];

  u16* Atb   = (u16*)d_ws;
  u16* Btb   = Atb + TAB_U16;
  int* flags = (int*)(Btb + TAB_U16);

  hipLaunchKernelGGL(mlp_kernel, dim3(512), dim3(256), 0, stream,
                     X, eidx, W1s, b1s, W2s, b2s, W1d, b1d, W2d, b2d, Atb, Btb, flags);
  hipLaunchKernelGGL(edge_kernel, dim3(E_EDGES / 512), dim3(256), 0, stream,
                     eidx, Atb, Btb, gamma, d_out, flags);
}